// Round 8
// baseline (111.580 us; speedup 1.0000x reference)
//
#include <hip/hip_runtime.h>
#include <hip/hip_bf16.h>

#define TT 2048
#define CC 1024
#define DD 128
#define BB 8
#define BK 32
#define NSTEP (CC / BK)   // 32 K-steps
#define SLOT_F 4160       // 32*128 O + 32 m + 32 l  (floats per partial slot)

typedef __attribute__((ext_vector_type(8))) short bf16x8;
typedef __attribute__((ext_vector_type(4))) float f32x4;
typedef __attribute__((ext_vector_type(16))) float f32x16;
typedef __attribute__((ext_vector_type(4))) short short4v;

__device__ inline short f2bf(float f) {
    union { float f; unsigned u; } v; v.f = f;
    unsigned r = v.u + 0x7FFFu + ((v.u >> 16) & 1u);   // RNE
    return (short)(r >> 16);
}

__device__ inline unsigned pack2(float lo, float hi) {  // two f32 -> packed bf16x2 word
    return (unsigned)(unsigned short)f2bf(lo) | ((unsigned)(unsigned short)f2bf(hi) << 16);
}

// async global->LDS, 16B per lane (guide §5 / Common-mistake #1)
#define GLOAD16(gp, lp) __builtin_amdgcn_global_load_lds(                       \
    (const __attribute__((address_space(1))) unsigned int*)(const void*)(gp),   \
    (__attribute__((address_space(3))) unsigned int*)(void*)(lp), 16, 0, 0)

// ---------------- Kernel 1: pack Wq|Wk|Wv -> bf16 Wall[384][1024] ----------------
__global__ void prep_w(const float* __restrict__ Wq, const float* __restrict__ Wk,
                       const float* __restrict__ Wv, short* __restrict__ Wall) {
    int row = blockIdx.x;  // 0..383
    const float* src = row < 128 ? Wq + (size_t)row * CC
                     : row < 256 ? Wk + (size_t)(row - 128) * CC
                                 : Wv + (size_t)(row - 256) * CC;
    short* dst = Wall + (size_t)row * CC;
    for (int j = threadIdx.x; j < CC; j += 256) dst[j] = f2bf(src[j]);
}

// ---------------- Kernel 1b: X fp32 -> bf16, streaming ----------------
__global__ __launch_bounds__(256) void xconv(const float* __restrict__ X, short* __restrict__ Xb) {
    size_t i = ((size_t)blockIdx.x * 256 + threadIdx.x) * 8;
    float4 f0 = *(const float4*)(X + i);
    float4 f1 = *(const float4*)(X + i + 4);
    bf16x8 t;
    t[0] = f2bf(f0.x); t[1] = f2bf(f0.y); t[2] = f2bf(f0.z); t[3] = f2bf(f0.w);
    t[4] = f2bf(f1.x); t[5] = f2bf(f1.y); t[6] = f2bf(f1.z); t[7] = f2bf(f1.w);
    *(bf16x8*)(Xb + i) = t;
}

// ---------------- Kernel 2: QKV GEMM, LDS-staged ----------------
__global__ __launch_bounds__(256) void qkv_gemm_lds(const short* __restrict__ Xb,
                                                    const short* __restrict__ Wall,
                                                    short* __restrict__ Q,
                                                    short* __restrict__ K,
                                                    short* __restrict__ Vt) {
    __shared__ char lds[2 * 12288];
    int tid = threadIdx.x, lane = tid & 63, wid = tid >> 6;
    int wm = wid >> 1, wn = wid & 1;          // 2x2 wave grid
    int lg = lane >> 4, lr = lane & 15;
    int m0 = blockIdx.x * 64;
    int n0 = blockIdx.y * 128;

    int arow = tid >> 2, achk = (tid & 3) * 8;         // staging coords
    const short* gA  = Xb   + (size_t)(m0 + arow) * CC + achk;
    const short* gB0 = Wall + (size_t)(n0 + arow) * CC + achk;
    const short* gB1 = gB0 + (size_t)64 * CC;

    f32x4 acc[2][4] = {};

#define STAGE(kb, buf) do {                                                     \
        char* base_ = lds + (buf) * 12288;                                      \
        GLOAD16(gA  + (kb), base_ + tid * 16);                                  \
        GLOAD16(gB0 + (kb), base_ + 4096 + tid * 16);                           \
        GLOAD16(gB1 + (kb), base_ + 8192 + tid * 16);                           \
    } while (0)

#define KSTEP(buf) do {                                                         \
        const char* base_ = lds + (buf) * 12288;                                \
        bf16x8 a_[2], b_[4];                                                    \
        _Pragma("unroll")                                                       \
        for (int mi = 0; mi < 2; ++mi)                                          \
            a_[mi] = *(const bf16x8*)(base_ + (wm*32 + mi*16 + lr) * 64 + lg*16);\
        _Pragma("unroll")                                                       \
        for (int nj = 0; nj < 4; ++nj)                                          \
            b_[nj] = *(const bf16x8*)(base_ + 4096 + (wn*64 + nj*16 + lr) * 64 + lg*16);\
        _Pragma("unroll")                                                       \
        for (int mi = 0; mi < 2; ++mi)                                          \
            _Pragma("unroll")                                                   \
            for (int nj = 0; nj < 4; ++nj)                                      \
                acc[mi][nj] = __builtin_amdgcn_mfma_f32_16x16x32_bf16(a_[mi], b_[nj], acc[mi][nj], 0, 0, 0);\
    } while (0)

    STAGE(0, 0);
#pragma unroll 2
    for (int t = 0; t < NSTEP; ++t) {
        __syncthreads();
        if (t + 1 < NSTEP) STAGE((t + 1) * BK, (t + 1) & 1);
        KSTEP(t & 1);
    }
#undef STAGE
#undef KSTEP

    int bidx = m0 >> 11;
    int nt = blockIdx.y;
#pragma unroll
    for (int mi = 0; mi < 2; ++mi) {
        int row = m0 + wm * 32 + mi * 16 + lg * 4;
        int t = row - bidx * TT;
#pragma unroll
        for (int nj = 0; nj < 4; ++nj) {
            int col = wn * 64 + nj * 16 + lr;
            if (nt == 0) {
                short* dst = Q + ((size_t)bidx * TT + t) * DD + col;
#pragma unroll
                for (int r = 0; r < 4; ++r) dst[(size_t)r * DD] = f2bf(acc[mi][nj][r]);
            } else if (nt == 1) {
                short* dst = K + ((size_t)bidx * TT + t) * DD + col;
#pragma unroll
                for (int r = 0; r < 4; ++r) dst[(size_t)r * DD] = f2bf(acc[mi][nj][r]);
            } else {
                short4v v4;
#pragma unroll
                for (int r = 0; r < 4; ++r) v4[r] = f2bf(acc[mi][nj][r]);
                *(short4v*)(Vt + ((size_t)bidx * DD + col) * TT + t) = v4;
            }
        }
    }
}

// ---------------- Kernel 2b: fallback (fp32 X, direct loads) ----------------
__global__ __launch_bounds__(512) void qkv_gemm(const float* __restrict__ X,
                                                const short* __restrict__ Wall,
                                                short* __restrict__ Q,
                                                short* __restrict__ K,
                                                short* __restrict__ Vt) {
    int tid = threadIdx.x, lane = tid & 63, wid = tid >> 6;
    int wm = wid >> 2, wn = wid & 3;
    int m0 = blockIdx.x * 64 + wm * 32;
    int n0 = wn * 96;
    int lg = lane >> 4, lr = lane & 15;

    f32x4 acc[2][6] = {};

    for (int kb = 0; kb < CC; kb += 32) {
        int kf = kb + lg * 8;
        bf16x8 a[2], bfr[6];
#pragma unroll
        for (int mi = 0; mi < 2; ++mi) {
            const float* p = X + (size_t)(m0 + mi * 16 + lr) * CC + kf;
            float4 f0 = *(const float4*)(p);
            float4 f1 = *(const float4*)(p + 4);
            bf16x8 t;
            t[0] = f2bf(f0.x); t[1] = f2bf(f0.y); t[2] = f2bf(f0.z); t[3] = f2bf(f0.w);
            t[4] = f2bf(f1.x); t[5] = f2bf(f1.y); t[6] = f2bf(f1.z); t[7] = f2bf(f1.w);
            a[mi] = t;
        }
#pragma unroll
        for (int nj = 0; nj < 6; ++nj)
            bfr[nj] = *(const bf16x8*)(Wall + (size_t)(n0 + nj * 16 + lr) * CC + kf);
#pragma unroll
        for (int mi = 0; mi < 2; ++mi)
#pragma unroll
            for (int nj = 0; nj < 6; ++nj)
                acc[mi][nj] = __builtin_amdgcn_mfma_f32_16x16x32_bf16(a[mi], bfr[nj], acc[mi][nj], 0, 0, 0);
    }

    int bidx = (blockIdx.x * 64) / TT;
#pragma unroll
    for (int mi = 0; mi < 2; ++mi) {
        int row = m0 + mi * 16 + lg * 4;
        int t = row - bidx * TT;
#pragma unroll
        for (int nj = 0; nj < 6; ++nj) {
            int col = n0 + nj * 16 + lr;
            if (col < 128) {
                short* dst = Q + ((size_t)bidx * TT + t) * DD + col;
#pragma unroll
                for (int r = 0; r < 4; ++r) dst[(size_t)r * DD] = f2bf(acc[mi][nj][r]);
            } else if (col < 256) {
                short* dst = K + ((size_t)bidx * TT + t) * DD + (col - 128);
#pragma unroll
                for (int r = 0; r < 4; ++r) dst[(size_t)r * DD] = f2bf(acc[mi][nj][r]);
            } else {
                short4v v4;
#pragma unroll
                for (int r = 0; r < 4; ++r) v4[r] = f2bf(acc[mi][nj][r]);
                *(short4v*)(Vt + ((size_t)bidx * DD + (col - 256)) * TT + t) = v4;
            }
        }
    }
}

// ---------------- Kernel 3: causal flash attention, 32x32 swapped-QK ----------------
// SPLIT=0: one block per (b,qtile), writes normalized out directly (verified r6 path).
// SPLIT=1: block = (b, qtile, split) over ~8 64-key units; writes unnormalized partial
// (O rel. to base m, plus m,l) to workspace; attn_combine merges & normalizes.
#define PV_CHUNK(WS, H, CB) do {                                                   \
    unsigned a0 = WS[4*(H)+0], a1 = WS[4*(H)+1];                                   \
    unsigned b0 = WS[4*(H)+2], b1 = WS[4*(H)+3];                                   \
    unsigned xa0 = (unsigned)__shfl_xor((int)a0, 32, 64);                          \
    unsigned xa1 = (unsigned)__shfl_xor((int)a1, 32, 64);                          \
    unsigned xb0 = (unsigned)__shfl_xor((int)b0, 32, 64);                          \
    unsigned xb1 = (unsigned)__shfl_xor((int)b1, 32, 64);                          \
    union { unsigned u[4]; bf16x8 v; } pu;                                         \
    pu.u[0] = lg2 ? xb0 : a0;   /* lo:(0,1)   hi:(8,9)   */                        \
    pu.u[1] = lg2 ? xb1 : a1;   /* lo:(2,3)   hi:(10,11) */                        \
    pu.u[2] = lg2 ? b0  : xa0;  /* lo:(4,5)   hi:(12,13) */                        \
    pu.u[3] = lg2 ? b1  : xa1;  /* lo:(6,7)   hi:(14,15) */                        \
    const short* Vp = Vb + kbase + (CB)*16 + lg2*8;                                \
    _Pragma("unroll")                                                              \
    for (int dt = 0; dt < 4; ++dt) {                                               \
        bf16x8 vf = *(const bf16x8*)(Vp + (size_t)(dt*32 + q) * TT);               \
        acc[dt] = __builtin_amdgcn_mfma_f32_32x32x16_bf16(vf, pu.v, acc[dt], 0,0,0);\
    }                                                                              \
} while (0)

template<int SPLIT>
__global__ __launch_bounds__(256) void attn32(const short* __restrict__ Q,
                                              const short* __restrict__ K,
                                              const short* __restrict__ Vt,
                                              float* __restrict__ out,
                                              float* __restrict__ part) {
    __shared__ float slot[2][4][32][33];
    __shared__ float ml[2][2][32];

    int tid = threadIdx.x;
    int lane = tid & 63, w = tid >> 6;
    int q = lane & 31, lg2 = lane >> 5;
    int bid = blockIdx.x;
    int b, qt, split, u0, u1;
    if constexpr (SPLIT) {
        b = bid & 7;
        int idx = 159 - (bid >> 3);             // heavy chunks first
        if (idx < 16)      { qt = idx;                     split = 0; }
        else if (idx < 48) { qt = 16 + ((idx - 16) >> 1);  split = (idx - 16) & 1; }
        else if (idx < 96) { qt = 32 + (idx - 48) / 3;     split = (idx - 48) % 3; }
        else               { qt = 48 + ((idx - 96) >> 2);  split = (idx - 96) & 3; }
        int units = (qt + 2) >> 1;
        int S = 1 + (qt >= 16) + (qt >= 32) + (qt >= 48);
        int ubase = units / S, urem = units % S;
        u0 = split * ubase + (split < urem ? split : urem);
        u1 = u0 + ubase + (split < urem ? 1 : 0);
    } else {
        b = bid & 7; qt = 63 - (bid >> 3); split = 0;
        u0 = 0; u1 = (qt + 2) >> 1;
    }
    int r0 = qt * 32;
    int qq = r0 + q;

    const short* Qb = Q + (size_t)b * TT * DD;
    const short* Kb = K + (size_t)b * TT * DD;
    const short* Vb = Vt + (size_t)b * DD * TT;

    bf16x8 qf[8];
#pragma unroll
    for (int kc = 0; kc < 8; ++kc)
        qf[kc] = *(const bf16x8*)(Qb + (size_t)qq * DD + kc * 16 + lg2 * 8);

    f32x16 acc[4] = {};
    float mb = -INFINITY, l = 0.f;
    const float scale = 0.08838834764831845f;

    for (int uu = u0 + w; uu < u1; uu += 4) {
        int kbase = uu * 64;
        f32x16 s0 = {}, s1 = {};
        const short* Kp0 = Kb + (size_t)(kbase + q) * DD + lg2 * 8;
        const short* Kp1 = Kp0 + (size_t)32 * DD;
#pragma unroll
        for (int kc = 0; kc < 8; ++kc) {
            bf16x8 k0 = *(const bf16x8*)(Kp0 + kc * 16);
            bf16x8 k1 = *(const bf16x8*)(Kp1 + kc * 16);
            s0 = __builtin_amdgcn_mfma_f32_32x32x16_bf16(k0, qf[kc], s0, 0, 0, 0);
            s1 = __builtin_amdgcn_mfma_f32_32x32x16_bf16(k1, qf[kc], s1, 0, 0, 0);
        }

        if (kbase + 63 > r0) {
#pragma unroll
            for (int r = 0; r < 16; ++r) {
                int kl = (r & 3) + 8 * (r >> 2) + 4 * lg2;
                s0[r] = (kbase + kl > qq) ? -INFINITY : s0[r] * scale;
                s1[r] = (kbase + 32 + kl > qq) ? -INFINITY : s1[r] * scale;
            }
        } else {
#pragma unroll
            for (int r = 0; r < 16; ++r) { s0[r] *= scale; s1[r] *= scale; }
        }

        float tmx[16];
#pragma unroll
        for (int r = 0; r < 16; ++r) tmx[r] = fmaxf(s0[r], s1[r]);
#pragma unroll
        for (int st = 8; st; st >>= 1)
#pragma unroll
            for (int r = 0; r < 8; ++r) if (r < st) tmx[r] = fmaxf(tmx[r], tmx[r + st]);
        float pm = fmaxf(tmx[0], __shfl_xor(tmx[0], 32, 64));

        if (__any(pm > mb + 8.f)) {
            float mn = fmaxf(mb, pm);
            float mc = (mn == -INFINITY) ? 0.f : mn;
            float sc = __expf(mb - mc);
            mb = mc; l *= sc;
#pragma unroll
            for (int dt = 0; dt < 4; ++dt)
#pragma unroll
                for (int r = 0; r < 16; ++r) acc[dt][r] *= sc;
        }

#pragma unroll
        for (int r = 0; r < 16; ++r) { s0[r] = __expf(s0[r] - mb); s1[r] = __expf(s1[r] - mb); }

        float ts[16];
#pragma unroll
        for (int r = 0; r < 16; ++r) ts[r] = s0[r] + s1[r];
#pragma unroll
        for (int st = 8; st; st >>= 1)
#pragma unroll
            for (int r = 0; r < 8; ++r) if (r < st) ts[r] += ts[r + st];
        l += ts[0] + __shfl_xor(ts[0], 32, 64);

        unsigned w0[8], w1[8];
#pragma unroll
        for (int k2 = 0; k2 < 8; ++k2) {
            w0[k2] = pack2(s0[2 * k2], s0[2 * k2 + 1]);
            w1[k2] = pack2(s1[2 * k2], s1[2 * k2 + 1]);
        }

        PV_CHUNK(w0, 0, 0);
        PV_CHUNK(w0, 1, 1);
        PV_CHUNK(w1, 0, 2);
        PV_CHUNK(w1, 1, 3);
    }

    // ---- tree combine of 4 wave partials through LDS ----
    if (w >= 2) {
        int s = w - 2;
#pragma unroll
        for (int dt = 0; dt < 4; ++dt)
#pragma unroll
            for (int r = 0; r < 16; ++r)
                slot[s][dt][(r & 3) + 8 * (r >> 2) + 4 * lg2][q] = acc[dt][r];
        if (lg2 == 0) { ml[s][0][q] = mb; ml[s][1][q] = l; }
    }
    __syncthreads();
    if (w < 2) {
        int s = w;
        float m2 = ml[s][0][q], l2 = ml[s][1][q];
        float M = fmaxf(mb, m2);
        float Mc = (M == -INFINITY) ? 0.f : M;
        float e1 = __expf(mb - Mc), e2 = __expf(m2 - Mc);
        mb = Mc; l = l * e1 + l2 * e2;
#pragma unroll
        for (int dt = 0; dt < 4; ++dt)
#pragma unroll
            for (int r = 0; r < 16; ++r)
                acc[dt][r] = acc[dt][r] * e1 + slot[s][dt][(r & 3) + 8 * (r >> 2) + 4 * lg2][q] * e2;
    }
    __syncthreads();
    if (w == 1) {
#pragma unroll
        for (int dt = 0; dt < 4; ++dt)
#pragma unroll
            for (int r = 0; r < 16; ++r)
                slot[0][dt][(r & 3) + 8 * (r >> 2) + 4 * lg2][q] = acc[dt][r];
        if (lg2 == 0) { ml[0][0][q] = mb; ml[0][1][q] = l; }
    }
    __syncthreads();
    if (w == 0) {
        float m2 = ml[0][0][q], l2 = ml[0][1][q];
        float M = fmaxf(mb, m2);
        float Mc = (M == -INFINITY) ? 0.f : M;
        float e1 = __expf(mb - Mc), e2 = __expf(m2 - Mc);
        float L = l * e1 + l2 * e2;
        if constexpr (SPLIT) {
            float* ps = part + (((size_t)b * 64 + qt) * 4 + split) * SLOT_F;
#pragma unroll
            for (int dt = 0; dt < 4; ++dt)
#pragma unroll
                for (int rq = 0; rq < 4; ++rq) {
                    f32x4 o4;
#pragma unroll
                    for (int j = 0; j < 4; ++j) {
                        int r = rq * 4 + j;
                        o4[j] = acc[dt][r] * e1 + slot[0][dt][(r & 3) + 8 * rq + 4 * lg2][q] * e2;
                    }
                    *(f32x4*)(ps + (size_t)q * 128 + dt * 32 + rq * 8 + lg2 * 4) = o4;
                }
            if (lg2 == 0) { ps[4096 + q] = Mc; ps[4128 + q] = L; }
        } else {
            float inv = 1.f / L;
#pragma unroll
            for (int dt = 0; dt < 4; ++dt)
#pragma unroll
                for (int rq = 0; rq < 4; ++rq) {
                    f32x4 o4;
#pragma unroll
                    for (int j = 0; j < 4; ++j) {
                        int r = rq * 4 + j;
                        o4[j] = (acc[dt][r] * e1 + slot[0][dt][(r & 3) + 8 * rq + 4 * lg2][q] * e2) * inv;
                    }
                    *(f32x4*)(out + ((size_t)b * TT + qq) * DD + dt * 32 + rq * 8 + lg2 * 4) = o4;
                }
        }
    }
}

// ---------------- Kernel 4: merge split partials, normalize ----------------
__global__ __launch_bounds__(256) void attn_combine(const float* __restrict__ part,
                                                    float* __restrict__ out) {
    int bid = blockIdx.x;              // 0..511 = b*64 + qt
    int b = bid >> 6, qt = bid & 63;
    int S = 1 + (qt >= 16) + (qt >= 32) + (qt >= 48);
    int t = threadIdx.x;
    int row = t >> 3, c0 = (t & 7) * 16;
    const float* base = part + (size_t)bid * 4 * SLOT_F;

    float m[4], l[4], e[4];
    float M = -INFINITY;
#pragma unroll
    for (int s = 0; s < 4; ++s) if (s < S) {
        m[s] = base[s * SLOT_F + 4096 + row];
        l[s] = base[s * SLOT_F + 4128 + row];
        M = fmaxf(M, m[s]);
    }
    float L = 0.f;
#pragma unroll
    for (int s = 0; s < 4; ++s) if (s < S) {
        e[s] = __expf(m[s] - M);
        L += l[s] * e[s];
    }
    float inv = 1.f / L;

    f32x4 o[4] = {};
#pragma unroll
    for (int s = 0; s < 4; ++s) if (s < S) {
        const float* p = base + s * SLOT_F + (size_t)row * 128 + c0;
#pragma unroll
        for (int j = 0; j < 4; ++j) {
            f32x4 v = *(const f32x4*)(p + j * 4);
            o[j] += v * e[s];
        }
    }
    float* op = out + ((size_t)b * TT + qt * 32 + row) * DD + c0;
#pragma unroll
    for (int j = 0; j < 4; ++j) *(f32x4*)(op + j * 4) = o[j] * inv;
}

extern "C" void kernel_launch(void* const* d_in, const int* in_sizes, int n_in,
                              void* d_out, int out_size, void* d_ws, size_t ws_size,
                              hipStream_t stream) {
    const float* x  = (const float*)d_in[0];
    const float* Wq = (const float*)d_in[1];
    const float* Wk = (const float*)d_in[2];
    const float* Wv = (const float*)d_in[3];
    float* out = (float*)d_out;

    char* ws = (char*)d_ws;
    short* Wall = (short*)ws;                              //    786,432 B
    short* Q    = (short*)(ws + 786432);                   //  4,194,304 B
    short* K    = (short*)(ws + 786432 + 4194304);
    short* Vt   = (short*)(ws + 786432 + 2 * 4194304);
    short* Xb   = (short*)(ws + 786432 + 3 * 4194304);     // 33,554,432 B
    float* Part = (float*)(ws + 786432 + 3 * 4194304 + 33554432);  // 34,078,720 B
    const size_t need_bf    = 786432 + 3ull * 4194304 + 33554432ull;
    const size_t need_split = need_bf + 512ull * 4 * SLOT_F * 4;

    prep_w<<<384, 256, 0, stream>>>(Wq, Wk, Wv, Wall);
    if (ws_size >= need_bf) {
        xconv<<<(16777216 / 8) / 256, 256, 0, stream>>>(x, Xb);
        qkv_gemm_lds<<<dim3(256, 3), 256, 0, stream>>>(Xb, Wall, Q, K, Vt);
    } else {
        qkv_gemm<<<16384 / 64, 512, 0, stream>>>(x, Wall, Q, K, Vt);
    }
    if (ws_size >= need_split) {
        attn32<1><<<BB * 160, 256, 0, stream>>>(Q, K, Vt, out, Part);
        attn_combine<<<512, 256, 0, stream>>>(Part, out);
    } else {
        attn32<0><<<BB * 64, 256, 0, stream>>>(Q, K, Vt, out, nullptr);
    }
}

// Round 9
// 85.946 us; speedup vs baseline: 1.2983x; 1.2983x over previous
//
#include <hip/hip_runtime.h>
#include <hip/hip_bf16.h>

#define TT 2048
#define CC 1024
#define DD 128
#define BB 8
#define BK 32
#define NSTEP (CC / BK)   // 32 K-steps

typedef __attribute__((ext_vector_type(8))) short bf16x8;
typedef __attribute__((ext_vector_type(4))) float f32x4;
typedef __attribute__((ext_vector_type(16))) float f32x16;
typedef __attribute__((ext_vector_type(4))) short short4v;

__device__ inline short f2bf(float f) {
    union { float f; unsigned u; } v; v.f = f;
    unsigned r = v.u + 0x7FFFu + ((v.u >> 16) & 1u);   // RNE
    return (short)(r >> 16);
}

__device__ inline unsigned pack2(float lo, float hi) {  // two f32 -> packed bf16x2 word
    return (unsigned)(unsigned short)f2bf(lo) | ((unsigned)(unsigned short)f2bf(hi) << 16);
}

// async global->LDS, 16B per lane (guide §5 / Common-mistake #1)
#define GLOAD16(gp, lp) __builtin_amdgcn_global_load_lds(                       \
    (const __attribute__((address_space(1))) unsigned int*)(const void*)(gp),   \
    (__attribute__((address_space(3))) unsigned int*)(void*)(lp), 16, 0, 0)

// ---------------- Kernel 1: pack Wq|Wk|Wv -> bf16 Wall[384][1024] ----------------
__global__ void prep_w(const float* __restrict__ Wq, const float* __restrict__ Wk,
                       const float* __restrict__ Wv, short* __restrict__ Wall) {
    int row = blockIdx.x;  // 0..383
    const float* src = row < 128 ? Wq + (size_t)row * CC
                     : row < 256 ? Wk + (size_t)(row - 128) * CC
                                 : Wv + (size_t)(row - 256) * CC;
    short* dst = Wall + (size_t)row * CC;
    for (int j = threadIdx.x; j < CC; j += 256) dst[j] = f2bf(src[j]);
}

// ---------------- Kernel 1b: X fp32 -> bf16, streaming ----------------
__global__ __launch_bounds__(256) void xconv(const float* __restrict__ X, short* __restrict__ Xb) {
    size_t i = ((size_t)blockIdx.x * 256 + threadIdx.x) * 8;
    float4 f0 = *(const float4*)(X + i);
    float4 f1 = *(const float4*)(X + i + 4);
    bf16x8 t;
    t[0] = f2bf(f0.x); t[1] = f2bf(f0.y); t[2] = f2bf(f0.z); t[3] = f2bf(f0.w);
    t[4] = f2bf(f1.x); t[5] = f2bf(f1.y); t[6] = f2bf(f1.z); t[7] = f2bf(f1.w);
    *(bf16x8*)(Xb + i) = t;
}

// ---------------- Kernel 2: QKV GEMM, LDS-staged ----------------
// V stored TILED: Vs[b][t>>4][d][t&15] so attention PV loads are contiguous
// (old [d][t] layout put 64 lanes at 4KB stride -> single-L2-channel pileup).
__global__ __launch_bounds__(256) void qkv_gemm_lds(const short* __restrict__ Xb,
                                                    const short* __restrict__ Wall,
                                                    short* __restrict__ Q,
                                                    short* __restrict__ K,
                                                    short* __restrict__ Vs) {
    __shared__ char lds[2 * 12288];
    int tid = threadIdx.x, lane = tid & 63, wid = tid >> 6;
    int wm = wid >> 1, wn = wid & 1;          // 2x2 wave grid
    int lg = lane >> 4, lr = lane & 15;
    int m0 = blockIdx.x * 64;
    int n0 = blockIdx.y * 128;

    int arow = tid >> 2, achk = (tid & 3) * 8;         // staging coords
    const short* gA  = Xb   + (size_t)(m0 + arow) * CC + achk;
    const short* gB0 = Wall + (size_t)(n0 + arow) * CC + achk;
    const short* gB1 = gB0 + (size_t)64 * CC;

    f32x4 acc[2][4] = {};

#define STAGE(kb, buf) do {                                                     \
        char* base_ = lds + (buf) * 12288;                                      \
        GLOAD16(gA  + (kb), base_ + tid * 16);                                  \
        GLOAD16(gB0 + (kb), base_ + 4096 + tid * 16);                           \
        GLOAD16(gB1 + (kb), base_ + 8192 + tid * 16);                           \
    } while (0)

#define KSTEP(buf) do {                                                         \
        const char* base_ = lds + (buf) * 12288;                                \
        bf16x8 a_[2], b_[4];                                                    \
        _Pragma("unroll")                                                       \
        for (int mi = 0; mi < 2; ++mi)                                          \
            a_[mi] = *(const bf16x8*)(base_ + (wm*32 + mi*16 + lr) * 64 + lg*16);\
        _Pragma("unroll")                                                       \
        for (int nj = 0; nj < 4; ++nj)                                          \
            b_[nj] = *(const bf16x8*)(base_ + 4096 + (wn*64 + nj*16 + lr) * 64 + lg*16);\
        _Pragma("unroll")                                                       \
        for (int mi = 0; mi < 2; ++mi)                                          \
            _Pragma("unroll")                                                   \
            for (int nj = 0; nj < 4; ++nj)                                      \
                acc[mi][nj] = __builtin_amdgcn_mfma_f32_16x16x32_bf16(a_[mi], b_[nj], acc[mi][nj], 0, 0, 0);\
    } while (0)

    STAGE(0, 0);
#pragma unroll 2
    for (int t = 0; t < NSTEP; ++t) {
        __syncthreads();
        if (t + 1 < NSTEP) STAGE((t + 1) * BK, (t + 1) & 1);
        KSTEP(t & 1);
    }
#undef STAGE
#undef KSTEP

    int bidx = m0 >> 11;
    int nt = blockIdx.y;
#pragma unroll
    for (int mi = 0; mi < 2; ++mi) {
        int row = m0 + wm * 32 + mi * 16 + lg * 4;
        int t = row - bidx * TT;
#pragma unroll
        for (int nj = 0; nj < 4; ++nj) {
            int col = wn * 64 + nj * 16 + lr;
            if (nt == 0) {
                short* dst = Q + ((size_t)bidx * TT + t) * DD + col;
#pragma unroll
                for (int r = 0; r < 4; ++r) dst[(size_t)r * DD] = f2bf(acc[mi][nj][r]);
            } else if (nt == 1) {
                short* dst = K + ((size_t)bidx * TT + t) * DD + col;
#pragma unroll
                for (int r = 0; r < 4; ++r) dst[(size_t)r * DD] = f2bf(acc[mi][nj][r]);
            } else {
                short4v v4;
#pragma unroll
                for (int r = 0; r < 4; ++r) v4[r] = f2bf(acc[mi][nj][r]);
                *(short4v*)(Vs + (size_t)bidx * TT * DD
                               + (size_t)(t >> 4) * 2048 + col * 16 + (t & 15)) = v4;
            }
        }
    }
}

// ---------------- Kernel 2b: fallback (fp32 X, direct loads) ----------------
__global__ __launch_bounds__(512) void qkv_gemm(const float* __restrict__ X,
                                                const short* __restrict__ Wall,
                                                short* __restrict__ Q,
                                                short* __restrict__ K,
                                                short* __restrict__ Vs) {
    int tid = threadIdx.x, lane = tid & 63, wid = tid >> 6;
    int wm = wid >> 2, wn = wid & 3;
    int m0 = blockIdx.x * 64 + wm * 32;
    int n0 = wn * 96;
    int lg = lane >> 4, lr = lane & 15;

    f32x4 acc[2][6] = {};

    for (int kb = 0; kb < CC; kb += 32) {
        int kf = kb + lg * 8;
        bf16x8 a[2], bfr[6];
#pragma unroll
        for (int mi = 0; mi < 2; ++mi) {
            const float* p = X + (size_t)(m0 + mi * 16 + lr) * CC + kf;
            float4 f0 = *(const float4*)(p);
            float4 f1 = *(const float4*)(p + 4);
            bf16x8 t;
            t[0] = f2bf(f0.x); t[1] = f2bf(f0.y); t[2] = f2bf(f0.z); t[3] = f2bf(f0.w);
            t[4] = f2bf(f1.x); t[5] = f2bf(f1.y); t[6] = f2bf(f1.z); t[7] = f2bf(f1.w);
            a[mi] = t;
        }
#pragma unroll
        for (int nj = 0; nj < 6; ++nj)
            bfr[nj] = *(const bf16x8*)(Wall + (size_t)(n0 + nj * 16 + lr) * CC + kf);
#pragma unroll
        for (int mi = 0; mi < 2; ++mi)
#pragma unroll
            for (int nj = 0; nj < 6; ++nj)
                acc[mi][nj] = __builtin_amdgcn_mfma_f32_16x16x32_bf16(a[mi], bfr[nj], acc[mi][nj], 0, 0, 0);
    }

    int bidx = (blockIdx.x * 64) / TT;
#pragma unroll
    for (int mi = 0; mi < 2; ++mi) {
        int row = m0 + mi * 16 + lg * 4;
        int t = row - bidx * TT;
#pragma unroll
        for (int nj = 0; nj < 6; ++nj) {
            int col = n0 + nj * 16 + lr;
            if (col < 128) {
                short* dst = Q + ((size_t)bidx * TT + t) * DD + col;
#pragma unroll
                for (int r = 0; r < 4; ++r) dst[(size_t)r * DD] = f2bf(acc[mi][nj][r]);
            } else if (col < 256) {
                short* dst = K + ((size_t)bidx * TT + t) * DD + (col - 128);
#pragma unroll
                for (int r = 0; r < 4; ++r) dst[(size_t)r * DD] = f2bf(acc[mi][nj][r]);
            } else {
                short4v v4;
#pragma unroll
                for (int r = 0; r < 4; ++r) v4[r] = f2bf(acc[mi][nj][r]);
                *(short4v*)(Vs + (size_t)bidx * TT * DD
                               + (size_t)(t >> 4) * 2048 + (col - 256) * 16 + (t & 15)) = v4;
            }
        }
    }
}

// ---------------- Kernel 3: causal flash attention, 32x32 swapped-QK ----------------
// (r6-verified structure; only the V access uses the new tiled layout:
//  Vs[b][k>>4][d][k&15] -> each dt-load covers a contiguous 1KB region.)
#define PV_CHUNK(WS, H, CB) do {                                                   \
    unsigned a0 = WS[4*(H)+0], a1 = WS[4*(H)+1];                                   \
    unsigned b0 = WS[4*(H)+2], b1 = WS[4*(H)+3];                                   \
    unsigned xa0 = (unsigned)__shfl_xor((int)a0, 32, 64);                          \
    unsigned xa1 = (unsigned)__shfl_xor((int)a1, 32, 64);                          \
    unsigned xb0 = (unsigned)__shfl_xor((int)b0, 32, 64);                          \
    unsigned xb1 = (unsigned)__shfl_xor((int)b1, 32, 64);                          \
    union { unsigned u[4]; bf16x8 v; } pu;                                         \
    pu.u[0] = lg2 ? xb0 : a0;   /* lo:(0,1)   hi:(8,9)   */                        \
    pu.u[1] = lg2 ? xb1 : a1;   /* lo:(2,3)   hi:(10,11) */                        \
    pu.u[2] = lg2 ? b0  : xa0;  /* lo:(4,5)   hi:(12,13) */                        \
    pu.u[3] = lg2 ? b1  : xa1;  /* lo:(6,7)   hi:(14,15) */                        \
    const short* Vp = Vb + ((size_t)((kbase >> 4) + (CB)) * 128 + q) * 16 + lg2 * 8;\
    _Pragma("unroll")                                                              \
    for (int dt = 0; dt < 4; ++dt) {                                               \
        bf16x8 vf = *(const bf16x8*)(Vp + dt * 512);                               \
        acc[dt] = __builtin_amdgcn_mfma_f32_32x32x16_bf16(vf, pu.v, acc[dt], 0,0,0);\
    }                                                                              \
} while (0)

__global__ __launch_bounds__(256) void attn32(const short* __restrict__ Q,
                                              const short* __restrict__ K,
                                              const short* __restrict__ Vt,
                                              float* __restrict__ out) {
    __shared__ float slot[2][4][32][33];
    __shared__ float ml[2][2][32];

    int tid = threadIdx.x;
    int lane = tid & 63, w = tid >> 6;
    int q = lane & 31, lg2 = lane >> 5;
    int bid = blockIdx.x;
    int b = bid & 7;
    int qt = 63 - (bid >> 3);
    int r0 = qt * 32;
    int qq = r0 + q;

    const short* Qb = Q + (size_t)b * TT * DD;
    const short* Kb = K + (size_t)b * TT * DD;
    const short* Vb = Vt + (size_t)b * TT * DD;

    bf16x8 qf[8];
#pragma unroll
    for (int kc = 0; kc < 8; ++kc)
        qf[kc] = *(const bf16x8*)(Qb + (size_t)qq * DD + kc * 16 + lg2 * 8);

    f32x16 acc[4] = {};
    float mb = -INFINITY, l = 0.f;
    const float scale = 0.08838834764831845f;
    int kend = r0 + 32;

    for (int kt = w; kt * 64 < kend; kt += 4) {
        int kbase = kt * 64;
        f32x16 s0 = {}, s1 = {};
        const short* Kp0 = Kb + (size_t)(kbase + q) * DD + lg2 * 8;
        const short* Kp1 = Kp0 + (size_t)32 * DD;
#pragma unroll
        for (int kc = 0; kc < 8; ++kc) {
            bf16x8 k0 = *(const bf16x8*)(Kp0 + kc * 16);
            bf16x8 k1 = *(const bf16x8*)(Kp1 + kc * 16);
            s0 = __builtin_amdgcn_mfma_f32_32x32x16_bf16(k0, qf[kc], s0, 0, 0, 0);
            s1 = __builtin_amdgcn_mfma_f32_32x32x16_bf16(k1, qf[kc], s1, 0, 0, 0);
        }

        if (kbase + 63 > r0) {
#pragma unroll
            for (int r = 0; r < 16; ++r) {
                int kl = (r & 3) + 8 * (r >> 2) + 4 * lg2;
                s0[r] = (kbase + kl > qq) ? -INFINITY : s0[r] * scale;
                s1[r] = (kbase + 32 + kl > qq) ? -INFINITY : s1[r] * scale;
            }
        } else {
#pragma unroll
            for (int r = 0; r < 16; ++r) { s0[r] *= scale; s1[r] *= scale; }
        }

        float tmx[16];
#pragma unroll
        for (int r = 0; r < 16; ++r) tmx[r] = fmaxf(s0[r], s1[r]);
#pragma unroll
        for (int st = 8; st; st >>= 1)
#pragma unroll
            for (int r = 0; r < 8; ++r) if (r < st) tmx[r] = fmaxf(tmx[r], tmx[r + st]);
        float pm = fmaxf(tmx[0], __shfl_xor(tmx[0], 32, 64));

        if (__any(pm > mb + 8.f)) {
            float mn = fmaxf(mb, pm);
            float mc = (mn == -INFINITY) ? 0.f : mn;
            float sc = __expf(mb - mc);
            mb = mc; l *= sc;
#pragma unroll
            for (int dt = 0; dt < 4; ++dt)
#pragma unroll
                for (int r = 0; r < 16; ++r) acc[dt][r] *= sc;
        }

#pragma unroll
        for (int r = 0; r < 16; ++r) { s0[r] = __expf(s0[r] - mb); s1[r] = __expf(s1[r] - mb); }

        float ts[16];
#pragma unroll
        for (int r = 0; r < 16; ++r) ts[r] = s0[r] + s1[r];
#pragma unroll
        for (int st = 8; st; st >>= 1)
#pragma unroll
            for (int r = 0; r < 8; ++r) if (r < st) ts[r] += ts[r + st];
        l += ts[0] + __shfl_xor(ts[0], 32, 64);

        unsigned w0[8], w1[8];
#pragma unroll
        for (int k2 = 0; k2 < 8; ++k2) {
            w0[k2] = pack2(s0[2 * k2], s0[2 * k2 + 1]);
            w1[k2] = pack2(s1[2 * k2], s1[2 * k2 + 1]);
        }

        PV_CHUNK(w0, 0, 0);
        PV_CHUNK(w0, 1, 1);
        PV_CHUNK(w1, 0, 2);
        PV_CHUNK(w1, 1, 3);
    }

    if (w >= 2) {
        int s = w - 2;
#pragma unroll
        for (int dt = 0; dt < 4; ++dt)
#pragma unroll
            for (int r = 0; r < 16; ++r)
                slot[s][dt][(r & 3) + 8 * (r >> 2) + 4 * lg2][q] = acc[dt][r];
        if (lg2 == 0) { ml[s][0][q] = mb; ml[s][1][q] = l; }
    }
    __syncthreads();
    if (w < 2) {
        int s = w;
        float m2 = ml[s][0][q], l2 = ml[s][1][q];
        float M = fmaxf(mb, m2);
        float Mc = (M == -INFINITY) ? 0.f : M;
        float e1 = __expf(mb - Mc), e2 = __expf(m2 - Mc);
        mb = Mc; l = l * e1 + l2 * e2;
#pragma unroll
        for (int dt = 0; dt < 4; ++dt)
#pragma unroll
            for (int r = 0; r < 16; ++r)
                acc[dt][r] = acc[dt][r] * e1 + slot[s][dt][(r & 3) + 8 * (r >> 2) + 4 * lg2][q] * e2;
    }
    __syncthreads();
    if (w == 1) {
#pragma unroll
        for (int dt = 0; dt < 4; ++dt)
#pragma unroll
            for (int r = 0; r < 16; ++r)
                slot[0][dt][(r & 3) + 8 * (r >> 2) + 4 * lg2][q] = acc[dt][r];
        if (lg2 == 0) { ml[0][0][q] = mb; ml[0][1][q] = l; }
    }
    __syncthreads();
    if (w == 0) {
        float m2 = ml[0][0][q], l2 = ml[0][1][q];
        float M = fmaxf(mb, m2);
        float Mc = (M == -INFINITY) ? 0.f : M;
        float e1 = __expf(mb - Mc), e2 = __expf(m2 - Mc);
        l = l * e1 + l2 * e2;
        float inv = 1.f / l;
#pragma unroll
        for (int dt = 0; dt < 4; ++dt)
#pragma unroll
            for (int rq = 0; rq < 4; ++rq) {
                f32x4 o4;
#pragma unroll
                for (int j = 0; j < 4; ++j) {
                    int r = rq * 4 + j;
                    o4[j] = (acc[dt][r] * e1 + slot[0][dt][(r & 3) + 8 * rq + 4 * lg2][q] * e2) * inv;
                }
                *(f32x4*)(out + ((size_t)b * TT + qq) * DD + dt * 32 + rq * 8 + lg2 * 4) = o4;
            }
    }
}

extern "C" void kernel_launch(void* const* d_in, const int* in_sizes, int n_in,
                              void* d_out, int out_size, void* d_ws, size_t ws_size,
                              hipStream_t stream) {
    const float* x  = (const float*)d_in[0];
    const float* Wq = (const float*)d_in[1];
    const float* Wk = (const float*)d_in[2];
    const float* Wv = (const float*)d_in[3];
    float* out = (float*)d_out;

    char* ws = (char*)d_ws;
    short* Wall = (short*)ws;                              //   786,432 B
    short* Q    = (short*)(ws + 786432);                   // 4,194,304 B
    short* K    = (short*)(ws + 786432 + 4194304);
    short* Vs   = (short*)(ws + 786432 + 2 * 4194304);
    short* Xb   = (short*)(ws + 786432 + 3 * 4194304);     // 33,554,432 B
    const size_t need_bf = 786432 + 3ull * 4194304 + 33554432ull;

    prep_w<<<384, 256, 0, stream>>>(Wq, Wk, Wv, Wall);
    if (ws_size >= need_bf) {
        xconv<<<(16777216 / 8) / 256, 256, 0, stream>>>(x, Xb);
        qkv_gemm_lds<<<dim3(256, 3), 256, 0, stream>>>(Xb, Wall, Q, K, Vs);
    } else {
        qkv_gemm<<<16384 / 64, 512, 0, stream>>>(x, Wall, Q, K, Vs);
    }
    attn32<<<BB * 64, 256, 0, stream>>>(Q, K, Vs, out);
}